// Round 1
// baseline (419.458 us; speedup 1.0000x reference)
//
#include <hip/hip_runtime.h>
#include <hip/hip_cooperative_groups.h>
#include <hip/hip_bf16.h>
#include <math.h>

#define NB 16      // batch
#define CS 80      // spec channels
#define T1 1000    // mel frames
#define CT 512     // text channels
#define T2 200     // phonemes
#define CA 80      // attn channels
#define GD 256     // speaker dim
#define C2T 1024   // 2*Ct
#define C2S 160    // 2*Cs
#define TEMP_F 0.0005f
#define ENC_STR 96 // padded row stride for k_encT/q_encT (zero-filled 80..95)
#define GRID 512   // cooperative grid: 2 blocks/CU x 256 CU

typedef __attribute__((ext_vector_type(8))) short short8;
typedef __attribute__((ext_vector_type(4))) float floatx4;

// fp32 -> bf16 bits, round-to-nearest-even
__device__ __forceinline__ short f2bf(float x) {
    unsigned u = __builtin_bit_cast(unsigned, x);
    unsigned r = (u + 0x7fffu + ((u >> 16) & 1u)) >> 16;
    return (short)r;
}

// ---------------------------------------------------------------------------
// weight pack into MFMA A-fragment-major layout:
//   wp[((co16*KW + k)*NC32 + ci32)*512 + lane*8 + j]
//   co = co16*16 + (lane&15), ci = ci32*32 + (lane>>4)*8 + j
// ---------------------------------------------------------------------------
template <int COUT, int CIN, int KW, int COP, int CINP>
__device__ __forceinline__ void wpack_body(const float* __restrict__ w,
                                           short* __restrict__ wp, int bid) {
    constexpr int NC32 = CINP / 32;
    constexpr int NFRAG = (COP / 16) * KW * NC32;
    int gid = bid * 256 + threadIdx.x;
    int frag = gid >> 6, lane = gid & 63;
    if (frag >= NFRAG) return;
    int co16 = frag / (KW * NC32), rem = frag - co16 * (KW * NC32);
    int k = rem / NC32, ci32 = rem - k * NC32;
    int co = co16 * 16 + (lane & 15);
    int ci = ci32 * 32 + (lane >> 4) * 8;
    short8 v;
#pragma unroll
    for (int j = 0; j < 8; j++) {
        float f = 0.f;
        if (co < COUT && ci + j < CIN) f = w[((size_t)co * CIN + ci + j) * KW + k];
        v[j] = f2bf(f);
    }
    *(short8*)(wp + (size_t)frag * 512 + lane * 8) = v;
}

// ---------------------------------------------------------------------------
// addspkT with inlined speaker projection:
// in fp32 [b][C][T] + (g[b]·w_spk[c] + b_spk[c]) -> out bf16 [b][T][C]
// ---------------------------------------------------------------------------
template <int C, int T>
__device__ __forceinline__ void addspkT_body(const float* __restrict__ in,
                                             const float* __restrict__ g,
                                             const float* __restrict__ w_spk,
                                             const float* __restrict__ b_spk,
                                             short* __restrict__ outT,
                                             float* sm, int bx, int by, int b) {
    float* spkS = sm;          // 32
    float* S = sm + 32;        // 32*65
    const int t0 = bx * 64, c0 = by * 32;
    const int tid = threadIdx.x;
    int cl = tid >> 3, part = tid & 7;
    int c = c0 + cl;
    float s = 0.f;
    if (c < C) {
        const float* wr = w_spk + (size_t)c * GD;
        const float* gr = g + b * GD;
        int j0 = part * 32;
#pragma unroll
        for (int j = 0; j < 32; j++) s += gr[j0 + j] * wr[j0 + j];
    }
    s += __shfl_xor(s, 1, 64); s += __shfl_xor(s, 2, 64); s += __shfl_xor(s, 4, 64);
    if (part == 0) spkS[cl] = s + ((c < C) ? b_spk[c] : 0.f);
    __syncthreads();
    for (int i = tid; i < 32 * 64; i += 256) {
        int cll = i >> 6, tl = i & 63;
        int gc = c0 + cll, gt = t0 + tl;
        float v = 0.f;
        if (gc < C && gt < T) v = in[((size_t)b * C + gc) * T + gt] + spkS[cll];
        S[cll * 65 + tl] = v;
    }
    __syncthreads();
    for (int i = tid; i < 64 * 32; i += 256) {
        int tl = i >> 5, cll = i & 31;
        int gt = t0 + tl, gc = c0 + cll;
        if (gc < C && gt < T) outT[((size_t)b * T + gt) * C + gc] = f2bf(S[cll * 65 + tl]);
    }
}

// ---------------------------------------------------------------------------
// conv3-as-GEMM body, W from global (A-frag layout), X in LDS.
// Single-buffered (27KB cap for 2-blocks/CU cooperative residency); next-chunk
// global loads are prefetched to registers, so HBM latency still overlaps MFMA.
// 16x16x32 bf16 MFMA: D lane reg r: row(co)=quad*4+r, col(t)=l16
// ---------------------------------------------------------------------------
template <int CIN, int COUT, int T, int KW, bool RELU, int CICH, int NC32T>
__device__ __forceinline__ void conv_body(const short* __restrict__ xT,
                                          const short* __restrict__ wp,
                                          const float* __restrict__ bias,
                                          short* __restrict__ outT,
                                          short* Xs, int bx, int by, int b) {
    constexpr int TT = 128, COT = 64;
    constexpr int PAD = KW / 2;
    constexpr int XROWS = TT + KW - 1;
    constexpr int PITCH = CICH + 8;
    constexpr int NPC = CICH / 8;
    constexpr int NC32 = CICH / 32;
    constexpr int CINP = NC32T * 32;
    constexpr int NCHK = CINP / CICH;
    constexpr int NPIECE = XROWS * NPC;
    constexpr int NLD = (NPIECE + 255) / 256;

    const int t0 = bx * TT, co0 = by * COT;
    const int tid = threadIdx.x, wave = tid >> 6, lane = tid & 63;
    const int quad = lane >> 4, l16 = lane & 15;
    const int wt = wave * 32;
    const int co16_0 = co0 >> 4;
    const short* xb = xT + (size_t)b * T * CIN;

    floatx4 acc[4][2];
#pragma unroll
    for (int mi = 0; mi < 4; mi++)
#pragma unroll
        for (int ni = 0; ni < 2; ni++) acc[mi][ni] = (floatx4){0.f, 0.f, 0.f, 0.f};

    for (int i = tid; i < NPIECE; i += 256) {
        int r = i / NPC, pp = i - r * NPC;
        int t = t0 + r - PAD, ci = pp * 8;
        uint4 v = {0u, 0u, 0u, 0u};
        if ((unsigned)t < (unsigned)T && ci + 8 <= CIN)
            v = *(const uint4*)(xb + (size_t)t * CIN + ci);
        *(uint4*)(Xs + r * PITCH + pp * 8) = v;
    }
    __syncthreads();

    for (int kc = 0; kc < NCHK; kc++) {
        uint4 tmp[NLD];
        if (NCHK > 1 && kc + 1 < NCHK) {
            int ci0n = (kc + 1) * CICH;
#pragma unroll
            for (int ld = 0; ld < NLD; ld++) {
                int i = tid + ld * 256;
                tmp[ld] = (uint4){0u, 0u, 0u, 0u};
                if (i < NPIECE) {
                    int r = i / NPC, pp = i - r * NPC;
                    int t = t0 + r - PAD, ci = ci0n + pp * 8;
                    if ((unsigned)t < (unsigned)T && ci + 8 <= CIN)
                        tmp[ld] = *(const uint4*)(xb + (size_t)t * CIN + ci);
                }
            }
        }
#pragma unroll
        for (int k = 0; k < KW; k++) {
#pragma unroll
            for (int kk = 0; kk < NC32; kk++) {
                int ci32 = kc * NC32 + kk;
                short8 a[4];
#pragma unroll
                for (int mi = 0; mi < 4; mi++)
                    a[mi] = *(const short8*)(wp +
                        ((size_t)((co16_0 + mi) * KW + k) * NC32T + ci32) * 512 + lane * 8);
#pragma unroll
                for (int ni = 0; ni < 2; ni++) {
                    short8 bb = *(const short8*)(Xs + (wt + ni * 16 + l16 + k) * PITCH +
                                                 kk * 32 + quad * 8);
#pragma unroll
                    for (int mi = 0; mi < 4; mi++)
                        acc[mi][ni] = __builtin_amdgcn_mfma_f32_16x16x32_bf16(a[mi], bb,
                                                                              acc[mi][ni], 0, 0, 0);
                }
            }
        }
        if (NCHK > 1 && kc + 1 < NCHK) {
            __syncthreads();
#pragma unroll
            for (int ld = 0; ld < NLD; ld++) {
                int i = tid + ld * 256;
                if (i < NPIECE) {
                    int r = i / NPC, pp = i - r * NPC;
                    *(uint4*)(Xs + r * PITCH + pp * 8) = tmp[ld];
                }
            }
            __syncthreads();
        }
    }
#pragma unroll
    for (int mi = 0; mi < 4; mi++) {
        int cb = co0 + mi * 16 + quad * 4;
        if (cb < COUT) {
            float4 bv = *(const float4*)(bias + cb);
#pragma unroll
            for (int ni = 0; ni < 2; ni++) {
                int t = t0 + wt + ni * 16 + l16;
                if (t < T) {
                    float v0 = acc[mi][ni][0] + bv.x, v1 = acc[mi][ni][1] + bv.y;
                    float v2 = acc[mi][ni][2] + bv.z, v3 = acc[mi][ni][3] + bv.w;
                    if (RELU) {
                        v0 = fmaxf(v0, 0.f); v1 = fmaxf(v1, 0.f);
                        v2 = fmaxf(v2, 0.f); v3 = fmaxf(v3, 0.f);
                    }
                    ushort4 o;
                    o.x = (unsigned short)f2bf(v0); o.y = (unsigned short)f2bf(v1);
                    o.z = (unsigned short)f2bf(v2); o.w = (unsigned short)f2bf(v3);
                    *(ushort4*)(outT + ((size_t)b * T + t) * COUT + cb) = o;
                }
            }
        }
    }
}

// ---------------------------------------------------------------------------
// key 1x1: full-K GEMM (K=1024), W from global frags, X single-buffered LDS
// with register prefetch. Emits k_encT (stride ENC_STR, zero pad) + k2 per row.
// ---------------------------------------------------------------------------
__device__ __forceinline__ void kgemm_body(const short* __restrict__ xT,
                                           const short* __restrict__ wp,
                                           const float* __restrict__ bias,
                                           short* __restrict__ outT,
                                           float* __restrict__ k2ws,
                                           short* sm, int bid) {
    constexpr int K = 1024, KCH = 128, PITCH = 136, NPC = 16, NCHK = 8;
    const int n0 = bid * 64;
    const int tid = threadIdx.x, wave = tid >> 6, lane = tid & 63;
    const int quad = lane >> 4, l16 = lane & 15;
    floatx4 acc[5];
#pragma unroll
    for (int mi = 0; mi < 5; mi++) acc[mi] = (floatx4){0.f, 0.f, 0.f, 0.f};

    for (int i = tid; i < 64 * NPC; i += 256) {
        int r = i / NPC, pp = i - r * NPC;
        *(uint4*)(sm + r * PITCH + pp * 8) = *(const uint4*)(xT + (size_t)(n0 + r) * K + pp * 8);
    }
    __syncthreads();
    for (int kc = 0; kc < NCHK; kc++) {
        uint4 tmp[4];
        if (kc + 1 < NCHK) {
            int ci0 = (kc + 1) * KCH;
#pragma unroll
            for (int ld = 0; ld < 4; ld++) {
                int i = tid + ld * 256;
                int r = i / NPC, pp = i - r * NPC;
                tmp[ld] = *(const uint4*)(xT + (size_t)(n0 + r) * K + ci0 + pp * 8);
            }
        }
#pragma unroll
        for (int kk = 0; kk < 4; kk++) {
            int ci32 = kc * 4 + kk;
            short8 bb = *(const short8*)(sm + (wave * 16 + l16) * PITCH + kk * 32 + quad * 8);
#pragma unroll
            for (int mi = 0; mi < 5; mi++) {
                short8 a = *(const short8*)(wp + ((size_t)(mi * 32 + ci32)) * 512 + lane * 8);
                acc[mi] = __builtin_amdgcn_mfma_f32_16x16x32_bf16(a, bb, acc[mi], 0, 0, 0);
            }
        }
        if (kc + 1 < NCHK) {
            __syncthreads();
#pragma unroll
            for (int ld = 0; ld < 4; ld++) {
                int i = tid + ld * 256;
                int r = i / NPC, pp = i - r * NPC;
                *(uint4*)(sm + r * PITCH + pp * 8) = tmp[ld];
            }
            __syncthreads();
        }
    }
    int n = n0 + wave * 16 + l16;
    float sq = 0.f;
#pragma unroll
    for (int mi = 0; mi < 5; mi++) {
        int cb = mi * 16 + quad * 4;
        float4 bv = *(const float4*)(bias + cb);
        float v0 = acc[mi][0] + bv.x, v1 = acc[mi][1] + bv.y;
        float v2 = acc[mi][2] + bv.z, v3 = acc[mi][3] + bv.w;
        sq += v0 * v0 + v1 * v1 + v2 * v2 + v3 * v3;
        ushort4 o;
        o.x = (unsigned short)f2bf(v0); o.y = (unsigned short)f2bf(v1);
        o.z = (unsigned short)f2bf(v2); o.w = (unsigned short)f2bf(v3);
        *(ushort4*)(outT + (size_t)n * ENC_STR + cb) = o;
    }
    if (quad < 2) *(uint4*)(outT + (size_t)n * ENC_STR + 80 + quad * 8) = (uint4){0u, 0u, 0u, 0u};
    sq += __shfl_xor(sq, 16, 64);
    sq += __shfl_xor(sq, 32, 64);
    if (quad == 0) k2ws[n] = sq;
}

// fused query conv2(relu)+conv3; H buffer aliases X buffer (X dead after conv2)
__device__ __forceinline__ void qconv23_body(const short* __restrict__ h1,
                                             const short* __restrict__ w2p,
                                             const float* __restrict__ b2,
                                             const short* __restrict__ w3p,
                                             const float* __restrict__ b3,
                                             short* __restrict__ outT, short* sm, int bid) {
    constexpr int K1 = 160, P1 = 168, NPC1 = 20, P3 = 104;
    short* Xs = sm;   // 64*168
    short* Hs = sm;   // aliased: Xs fully consumed before Hs is written
    const int n0 = bid * 64;
    const int tid = threadIdx.x, wave = tid >> 6, lane = tid & 63;
    const int quad = lane >> 4, l16 = lane & 15;

    for (int i = tid; i < 64 * NPC1; i += 256) {
        int r = i / NPC1, pp = i - r * NPC1;
        *(uint4*)(Xs + r * P1 + pp * 8) = *(const uint4*)(h1 + (size_t)(n0 + r) * K1 + pp * 8);
    }
    __syncthreads();

    floatx4 acc[5];
#pragma unroll
    for (int mi = 0; mi < 5; mi++) acc[mi] = (floatx4){0.f, 0.f, 0.f, 0.f};
#pragma unroll
    for (int kk = 0; kk < 5; kk++) {
        short8 bb = *(const short8*)(Xs + (wave * 16 + l16) * P1 + kk * 32 + quad * 8);
#pragma unroll
        for (int mi = 0; mi < 5; mi++) {
            short8 a = *(const short8*)(w2p + ((size_t)(mi * 5 + kk)) * 512 + lane * 8);
            acc[mi] = __builtin_amdgcn_mfma_f32_16x16x32_bf16(a, bb, acc[mi], 0, 0, 0);
        }
    }
    __syncthreads();   // all Xs reads done before alias overwrite
#pragma unroll
    for (int mi = 0; mi < 5; mi++) {
        int cb = mi * 16 + quad * 4;
        float4 bv = *(const float4*)(b2 + cb);
        ushort4 o;
        o.x = (unsigned short)f2bf(fmaxf(acc[mi][0] + bv.x, 0.f));
        o.y = (unsigned short)f2bf(fmaxf(acc[mi][1] + bv.y, 0.f));
        o.z = (unsigned short)f2bf(fmaxf(acc[mi][2] + bv.z, 0.f));
        o.w = (unsigned short)f2bf(fmaxf(acc[mi][3] + bv.w, 0.f));
        *(ushort4*)(Hs + (wave * 16 + l16) * P3 + cb) = o;
    }
    if (quad < 3) *(uint4*)(Hs + (wave * 16 + l16) * P3 + 80 + quad * 8) = (uint4){0u, 0u, 0u, 0u};
    __syncthreads();

    floatx4 acc3[5];
#pragma unroll
    for (int mi = 0; mi < 5; mi++) acc3[mi] = (floatx4){0.f, 0.f, 0.f, 0.f};
#pragma unroll
    for (int kk = 0; kk < 3; kk++) {
        short8 bb = *(const short8*)(Hs + (wave * 16 + l16) * P3 + kk * 32 + quad * 8);
#pragma unroll
        for (int mi = 0; mi < 5; mi++) {
            short8 a = *(const short8*)(w3p + ((size_t)(mi * 3 + kk)) * 512 + lane * 8);
            acc3[mi] = __builtin_amdgcn_mfma_f32_16x16x32_bf16(a, bb, acc3[mi], 0, 0, 0);
        }
    }
    int n = n0 + wave * 16 + l16;
#pragma unroll
    for (int mi = 0; mi < 5; mi++) {
        int cb = mi * 16 + quad * 4;
        float4 bv = *(const float4*)(b3 + cb);
        ushort4 o;
        o.x = (unsigned short)f2bf(acc3[mi][0] + bv.x);
        o.y = (unsigned short)f2bf(acc3[mi][1] + bv.y);
        o.z = (unsigned short)f2bf(acc3[mi][2] + bv.z);
        o.w = (unsigned short)f2bf(acc3[mi][3] + bv.w);
        *(ushort4*)(outT + (size_t)n * ENC_STR + cb) = o;
    }
    if (quad < 2) *(uint4*)(outT + (size_t)n * ENC_STR + 80 + quad * 8) = (uint4){0u, 0u, 0u, 0u};
}

// ---------------------------------------------------------------------------
// attention body: LDS-free, barrier-free (unchanged math)
// ---------------------------------------------------------------------------
__device__ __forceinline__ float rmax16(float v) {
#pragma unroll
    for (int o = 1; o < 16; o <<= 1) v = fmaxf(v, __shfl_xor(v, o, 64));
    return v;
}
__device__ __forceinline__ float rsum16(float v) {
#pragma unroll
    for (int o = 1; o < 16; o <<= 1) v += __shfl_xor(v, o, 64);
    return v;
}

__device__ __forceinline__ void attn_body(int tix, int b,
                                          const short* __restrict__ q_encT,
                                          const short* __restrict__ k_encT,
                                          const float* __restrict__ k2ws,
                                          const float* __restrict__ prior,
                                          const int* __restrict__ mask,
                                          float* __restrict__ out_attn,
                                          float* __restrict__ out_logp) {
    const int t10 = tix * 64;
    const int tid = threadIdx.x, wave = tid >> 6, lane = tid & 63;
    const int quad = lane >> 4, l16 = lane & 15;

    float k2v[13]; int mskv[13];
#pragma unroll
    for (int n = 0; n < 13; n++) {
        int t2 = n * 16 + l16, t2c = t2 < T2 ? t2 : T2 - 1;
        k2v[n] = k2ws[b * T2 + t2c];
        mskv[n] = (t2 < T2) ? mask[b * T2 + t2] : 0;
    }
    const int t1base = t10 + wave * 16 + quad * 4;
    float pr[4][13];
#pragma unroll
    for (int r = 0; r < 4; r++) {
        int t1 = t1base + r, t1c = t1 < T1 ? t1 : T1 - 1;
#pragma unroll
        for (int n = 0; n < 13; n++) {
            int t2 = n * 16 + l16, t2c = t2 < T2 ? t2 : T2 - 1;
            pr[r][n] = prior[((size_t)b * T1 + t1c) * T2 + t2c];
        }
    }

    floatx4 acc[13];
#pragma unroll
    for (int n = 0; n < 13; n++) acc[n] = (floatx4){0.f, 0.f, 0.f, 0.f};
    const short* qb = q_encT + ((size_t)(b * T1 + t10 + wave * 16 + l16)) * ENC_STR + quad * 8;
    const short* kb = k_encT + ((size_t)(b * T2 + l16)) * ENC_STR + quad * 8;
#pragma unroll
    for (int kk = 0; kk < 3; kk++) {
        short8 a = *(const short8*)(qb + kk * 32);
#pragma unroll
        for (int n = 0; n < 13; n++) {
            short8 bb = *(const short8*)(kb + (size_t)n * 16 * ENC_STR + kk * 32);
            acc[n] = __builtin_amdgcn_mfma_f32_16x16x32_bf16(a, bb, acc[n], 0, 0, 0);
        }
    }

#pragma unroll
    for (int r = 0; r < 4; r++) {
        int t1 = t1base + r;
        bool t1ok = t1 < T1;
        float s[13], u[13];
        float mx = -INFINITY, mxu = -INFINITY;
#pragma unroll
        for (int n = 0; n < 13; n++) {
            int t2 = n * 16 + l16;
            float sv = (t2 < T2) ? TEMP_F * (2.f * acc[n][r] - k2v[n]) : -INFINITY;
            s[n] = sv;
            float uv = (t2 < T2) ? sv + __logf(pr[r][n] + 1e-8f) : -INFINITY;
            u[n] = uv;
            mx = fmaxf(mx, sv);
            mxu = fmaxf(mxu, (mskv[n] != 0) ? uv : -INFINITY);
        }
        float m = rmax16(mx);
        float m2 = rmax16(mxu);
        float se = 0.f, se2 = 0.f;
        float e2v[13];
#pragma unroll
        for (int n = 0; n < 13; n++) {
            se += (s[n] == -INFINITY) ? 0.f : __expf(s[n] - m);
            float e2 = (mskv[n] != 0) ? __expf(u[n] - m2) : 0.f;
            e2v[n] = e2;
            se2 += e2;
        }
        float logZ = __logf(rsum16(se));
        float invZ2 = 1.f / rsum16(se2);
        if (t1ok) {
#pragma unroll
            for (int n = 0; n < 13; n++) {
                int t2 = n * 16 + l16;
                if (t2 < T2) {
                    size_t o = ((size_t)b * T1 + t1) * T2 + t2;
                    out_attn[o] = e2v[n] * invZ2;
                    out_logp[o] = u[n] - m - logZ;
                }
            }
        }
    }
}

// ---------------------------------------------------------------------------
// params + phase dispatchers
// ---------------------------------------------------------------------------
struct KP {
    const float* queries; const float* keys; const int* mask; const float* prior; const float* g;
    const float* wk1; const float* bk1; const float* wk2; const float* bk2;
    const float* wq1; const float* bq1; const float* wq2; const float* bq2;
    const float* wq3; const float* bq3;
    const float* w_kspk; const float* b_kspk; const float* w_qspk; const float* b_qspk;
    short* wk1p; short* wq1p; short* wk2p; short* wq2p; short* wq3p;
    short* xkT; short* xqT; short* k_encT; short* q_encT; float* k2ws;
    short* kh1T; short* qh1T; float* out_attn; float* out_logp;
};

#define NPREP 2638
#define NCONV 896

__device__ __forceinline__ void prep_virt(int bid, const KP& p, float* smF) {
    if (bid < 768) { wpack_body<C2T, CT, 3, C2T, CT>(p.wk1, p.wk1p, bid); return; }
    bid -= 768;
    if (bid < 27) { wpack_body<C2S, CS, 3, 192, 96>(p.wq1, p.wq1p, bid); return; }
    bid -= 27;
    if (bid < 40) { wpack_body<CA, C2T, 1, 80, 1024>(p.wk2, p.wk2p, bid); return; }
    bid -= 40;
    if (bid < 7) { wpack_body<CA, C2S, 1, 80, 160>(p.wq2, p.wq2p, bid); return; }
    bid -= 7;
    if (bid < 4) { wpack_body<CA, CS, 1, 80, 96>(p.wq3, p.wq3p, bid); return; }
    bid -= 4;
    if (bid < 1024) {
        int bx = bid & 3, by = (bid >> 2) & 15, b = bid >> 6;
        addspkT_body<CT, T2>(p.keys, p.g, p.w_kspk, p.b_kspk, p.xkT, smF, bx, by, b);
        return;
    }
    bid -= 1024;
    {
        int bx = bid & 15, by = (bid >> 4) % 3, b = bid / 48;
        addspkT_body<CS, T1>(p.queries, p.g, p.w_qspk, p.b_qspk, p.xqT, smF, bx, by, b);
    }
}

__device__ __forceinline__ void conv_virt(int bid, const KP& p, short* sm) {
    if (bid < 512) {
        int bx = bid & 1, by = (bid >> 1) & 15, b = bid >> 5;
        conv_body<CT, C2T, T2, 3, true, 64, 16>(p.xkT, p.wk1p, p.bk1, p.kh1T, sm, bx, by, b);
    } else {
        int r = bid - 512;
        int bx = r & 7, by = (r >> 3) % 3, b = r / 24;
        conv_body<CS, C2S, T1, 3, true, 96, 3>(p.xqT, p.wq1p, p.bq1, p.qh1T, sm, bx, by, b);
    }
}

// ---------------------------------------------------------------------------
// fused cooperative kernel: P -> C -> G -> A with grid syncs.
// LDS max over phases = query-conv 130*104 shorts = 27040 B -> 2 blocks/CU
// even under 64KB/CU accounting.
// ---------------------------------------------------------------------------
__global__ __launch_bounds__(256, 2) void fused_all(KP p) {
    __shared__ __align__(16) short smS[13520];
    cooperative_groups::grid_group gg = cooperative_groups::this_grid();

    // P: prep (weight pack + speaker-add/transpose)
    for (int vb = blockIdx.x; vb < NPREP; vb += GRID) {
        __syncthreads();
        prep_virt(vb, p, (float*)smS);
    }
    gg.sync();

    // C: both k=3 convs
    for (int vb = blockIdx.x; vb < NCONV; vb += GRID) {
        __syncthreads();
        conv_virt(vb, p, smS);
    }
    gg.sync();

    // G: key 1x1 GEMM + fused query conv2/conv3 (300 of 512 blocks active)
    if (blockIdx.x < 50)
        kgemm_body(p.kh1T, p.wk2p, p.bk2, p.k_encT, p.k2ws, smS, blockIdx.x);
    else if (blockIdx.x < 300)
        qconv23_body(p.qh1T, p.wq2p, p.bq2, p.wq3p, p.bq3, p.q_encT, smS, blockIdx.x - 50);
    gg.sync();

    // A: attention (256 of 512 blocks active)
    if (blockIdx.x < 256)
        attn_body(blockIdx.x & 15, blockIdx.x >> 4, p.q_encT, p.k_encT, p.k2ws,
                  p.prior, p.mask, p.out_attn, p.out_logp);
}

// ---------------------------------------------------------------------------
// fallback: original 4-dispatch pipeline (same bodies), used only if the
// cooperative launch is rejected by the runtime.
// ---------------------------------------------------------------------------
__global__ __launch_bounds__(256) void prep_kernel_fb(KP p) {
    __shared__ __align__(16) float smF[32 + 32 * 65];
    prep_virt(blockIdx.x, p, smF);
}
__global__ __launch_bounds__(256, 2) void conv_kernel_fb(KP p) {
    __shared__ __align__(16) short sm[13520];
    conv_virt(blockIdx.x, p, sm);
}
__global__ __launch_bounds__(256, 2) void gemm_kernel_fb(KP p) {
    __shared__ __align__(16) short sm[10752];
    int bid = blockIdx.x;
    if (bid < 50) kgemm_body(p.kh1T, p.wk2p, p.bk2, p.k_encT, p.k2ws, sm, bid);
    else qconv23_body(p.qh1T, p.wq2p, p.bq2, p.wq3p, p.bq3, p.q_encT, sm, bid - 50);
}
__global__ __launch_bounds__(256) void attn_kernel_fb(KP p) {
    attn_body(blockIdx.x, blockIdx.y, p.q_encT, p.k_encT, p.k2ws, p.prior, p.mask,
              p.out_attn, p.out_logp);
}

// ---------------------------------------------------------------------------
extern "C" void kernel_launch(void* const* d_in, const int* in_sizes, int n_in,
                              void* d_out, int out_size, void* d_ws, size_t ws_size,
                              hipStream_t stream) {
    KP p;
    p.queries = (const float*)d_in[0];
    p.keys    = (const float*)d_in[1];
    p.mask    = (const int*)d_in[2];
    p.prior   = (const float*)d_in[3];
    p.g       = (const float*)d_in[4];
    p.wk1 = (const float*)d_in[5];  p.bk1 = (const float*)d_in[6];
    p.wk2 = (const float*)d_in[7];  p.bk2 = (const float*)d_in[8];
    p.wq1 = (const float*)d_in[9];  p.bq1 = (const float*)d_in[10];
    p.wq2 = (const float*)d_in[11]; p.bq2 = (const float*)d_in[12];
    p.wq3 = (const float*)d_in[13]; p.bq3 = (const float*)d_in[14];
    p.w_kspk = (const float*)d_in[15]; p.b_kspk = (const float*)d_in[16];
    p.w_qspk = (const float*)d_in[17]; p.b_qspk = (const float*)d_in[18];

    // ---- workspace layout (shorts) ----
    short* wsS = (short*)d_ws;
    p.xkT   = wsS;                        // 16x200x512        -> 1,638,400
    p.xqT   = wsS + 1638400;              // 16x1000x80        -> 2,918,400
    p.wk1p  = wsS + 2918400;              // 3072 frags        -> 4,491,264
    p.wq1p  = wsS + 4491264;              // 108 frags         -> 4,546,560
    p.wk2p  = wsS + 4546560;              // 160 frags         -> 4,628,480
    p.wq2p  = wsS + 4628480;              // 25 frags          -> 4,641,280
    p.wq3p  = wsS + 4641280;              // 15 frags          -> 4,648,960
    p.k_encT = wsS + 4648960;             // 3216 x 96         -> 4,957,696
    p.q_encT = wsS + 4957696;             // 16032 x 96        -> 6,496,768
    p.k2ws  = (float*)d_ws + 3248384;     // 3200 fp32
    // hidden layers in d_out (consumed before attn overwrites):
    short* doS = (short*)d_out;
    p.kh1T = doS;                         // 3200x1024 (6.55 MB)
    p.qh1T = doS + 3276800;               // 16000x160 (5.12 MB)
    p.out_attn = (float*)d_out;
    p.out_logp = (float*)d_out + (size_t)NB * T1 * T2;

    void* kargs[] = { (void*)&p };
    hipError_t e = hipLaunchCooperativeKernel((const void*)fused_all, dim3(GRID), dim3(256),
                                              kargs, 0, stream);
    if (e != hipSuccess) {
        // fallback: original 4-dispatch pipeline
        prep_kernel_fb<<<dim3(NPREP), dim3(256), 0, stream>>>(p);
        conv_kernel_fb<<<dim3(NCONV), dim3(256), 0, stream>>>(p);
        gemm_kernel_fb<<<dim3(300), dim3(256), 0, stream>>>(p);
        attn_kernel_fb<<<dim3(16, NB), dim3(256), 0, stream>>>(p);
    }
}

// Round 2
// 190.682 us; speedup vs baseline: 2.1998x; 2.1998x over previous
//
#include <hip/hip_runtime.h>
#include <hip/hip_bf16.h>
#include <math.h>

#define NB 16      // batch
#define CS 80      // spec channels
#define T1 1000    // mel frames
#define CT 512     // text channels
#define T2 200     // phonemes
#define CA 80      // attn channels
#define GD 256     // speaker dim
#define C2T 1024   // 2*Ct
#define C2S 160    // 2*Cs
#define TEMP_F 0.0005f
#define ENC_STR 96 // padded row stride for k_encT/q_encT (zero-filled 80..95)
#define WPITCH 388 // fp32 LDS pitch for wk1 pack staging (16B-aligned rows)

typedef __attribute__((ext_vector_type(8))) short short8;
typedef __attribute__((ext_vector_type(4))) float floatx4;

// fp32 -> bf16 bits, round-to-nearest-even
__device__ __forceinline__ short f2bf(float x) {
    unsigned u = __builtin_bit_cast(unsigned, x);
    unsigned r = (u + 0x7fffu + ((u >> 16) & 1u)) >> 16;
    return (short)r;
}

// ---------------------------------------------------------------------------
// params
// ---------------------------------------------------------------------------
struct KP {
    const float* queries; const float* keys; const int* mask; const float* prior; const float* g;
    const float* wk1; const float* bk1; const float* wk2; const float* bk2;
    const float* wq1; const float* bq1; const float* wq2; const float* bq2;
    const float* wq3; const float* bq3;
    const float* w_kspk; const float* b_kspk; const float* w_qspk; const float* b_qspk;
    short* wk1p; short* wq1p; short* wk2p; short* wq2p; short* wq3p;
    short* xkT; short* xqT; short* k_encT; short* q_encT; float* k2ws;
    short* kh1T; short* qh1T; float* out_attn; float* out_logp;
};

// ---------------------------------------------------------------------------
// generic weight pack into MFMA A-fragment-major layout (scalar loads):
//   wp[((co16*KW + k)*NC32 + ci32)*512 + lane*8 + j]
//   co = co16*16 + (lane&15), ci = ci32*32 + (lane>>4)*8 + j
// ---------------------------------------------------------------------------
template <int COUT, int CIN, int KW, int COP, int CINP>
__device__ __forceinline__ void wpack_body(const float* __restrict__ w,
                                           short* __restrict__ wp, int bid) {
    constexpr int NC32 = CINP / 32;
    constexpr int NFRAG = (COP / 16) * KW * NC32;
    int gid = bid * 256 + threadIdx.x;
    int frag = gid >> 6, lane = gid & 63;
    if (frag >= NFRAG) return;
    int co16 = frag / (KW * NC32), rem = frag - co16 * (KW * NC32);
    int k = rem / NC32, ci32 = rem - k * NC32;
    int co = co16 * 16 + (lane & 15);
    int ci = ci32 * 32 + (lane >> 4) * 8;
    short8 v;
#pragma unroll
    for (int j = 0; j < 8; j++) {
        float f = 0.f;
        if (co < COUT && ci + j < CIN) f = w[((size_t)co * CIN + ci + j) * KW + k];
        v[j] = f2bf(f);
    }
    *(short8*)(wp + (size_t)frag * 512 + lane * 8) = v;
}

// ---------------------------------------------------------------------------
// KW==1 pack: ci contiguous in memory -> vector float4 loads
// ---------------------------------------------------------------------------
template <int COUT, int CIN, int COP, int CINP>
__device__ __forceinline__ void wpack1_body(const float* __restrict__ w,
                                            short* __restrict__ wp, int bid) {
    constexpr int NC32 = CINP / 32;
    constexpr int NFRAG = (COP / 16) * NC32;
    int gid = bid * 256 + threadIdx.x;
    int frag = gid >> 6, lane = gid & 63;
    if (frag >= NFRAG) return;
    int co16 = frag / NC32, ci32 = frag - co16 * NC32;
    int co = co16 * 16 + (lane & 15);
    int ci = ci32 * 32 + (lane >> 4) * 8;
    short8 v;
    if (co < COUT && ci + 8 <= CIN) {
        const float* src = w + (size_t)co * CIN + ci;
        float4 f0 = *(const float4*)src;
        float4 f1 = *(const float4*)(src + 4);
        v[0] = f2bf(f0.x); v[1] = f2bf(f0.y); v[2] = f2bf(f0.z); v[3] = f2bf(f0.w);
        v[4] = f2bf(f1.x); v[5] = f2bf(f1.y); v[6] = f2bf(f1.z); v[7] = f2bf(f1.w);
    } else {
#pragma unroll
        for (int j = 0; j < 8; j++) {
            float f = 0.f;
            if (co < COUT && ci + j < CIN) f = w[(size_t)co * CIN + ci + j];
            v[j] = f2bf(f);
        }
    }
    *(short8*)(wp + (size_t)frag * 512 + lane * 8) = v;
}

// ---------------------------------------------------------------------------
// wk1 pack via LDS staging: coalesced float4 global loads, scattered LDS reads.
// Block covers (co16 = bid>>2, ci-quarter cq = bid&3); emits all 12 frags
// (3 taps x 4 ci32) for that region. wk1: COUT=1024, CIN=512, KW=3.
// ---------------------------------------------------------------------------
__device__ __forceinline__ void wpack_k1_lds(const float* __restrict__ w,
                                             short* __restrict__ wp,
                                             float* smW, int bid) {
    const int tid = threadIdx.x;
    const int co16 = bid >> 2, cq = bid & 3;
    const float* src = w + (size_t)co16 * 16 * 1536 + cq * 384;
#pragma unroll
    for (int it = 0; it < 6; it++) {
        int i = tid + it * 256;             // 1536 float4 pieces: 16 rows x 96
        int row = i / 96, colv = i - row * 96;
        *(float4*)(smW + row * WPITCH + colv * 4) =
            *(const float4*)(src + (size_t)row * 1536 + colv * 4);
    }
    __syncthreads();
    const int wv = tid >> 6, lane = tid & 63;
    const int r = lane & 15, hi = lane >> 4;
#pragma unroll
    for (int fo = 0; fo < 3; fo++) {
        int f = fo * 4 + wv;                // 0..11
        int k = f >> 2, ci32l = f & 3;
        int frag = (co16 * 3 + k) * 16 + (cq * 4 + ci32l);
        const float* base = smW + r * WPITCH + (ci32l * 32 + hi * 8) * 3 + k;
        short8 v;
#pragma unroll
        for (int j = 0; j < 8; j++) v[j] = f2bf(base[j * 3]);
        *(short8*)(wp + (size_t)frag * 512 + lane * 8) = v;
    }
}

// ---------------------------------------------------------------------------
// addspkT with inlined speaker projection:
// in fp32 [b][C][T] + (g[b]·w_spk[c] + b_spk[c]) -> out bf16 [b][T][C]
// ---------------------------------------------------------------------------
template <int C, int T>
__device__ __forceinline__ void addspkT_body(const float* __restrict__ in,
                                             const float* __restrict__ g,
                                             const float* __restrict__ w_spk,
                                             const float* __restrict__ b_spk,
                                             short* __restrict__ outT,
                                             float* sm, int bx, int by, int b) {
    float* spkS = sm;          // 32
    float* S = sm + 32;        // 32*65
    const int t0 = bx * 64, c0 = by * 32;
    const int tid = threadIdx.x;
    int cl = tid >> 3, part = tid & 7;
    int c = c0 + cl;
    float s = 0.f;
    if (c < C) {
        const float* wr = w_spk + (size_t)c * GD;
        const float* gr = g + b * GD;
        int j0 = part * 32;
#pragma unroll
        for (int j = 0; j < 32; j++) s += gr[j0 + j] * wr[j0 + j];
    }
    s += __shfl_xor(s, 1, 64); s += __shfl_xor(s, 2, 64); s += __shfl_xor(s, 4, 64);
    if (part == 0) spkS[cl] = s + ((c < C) ? b_spk[c] : 0.f);
    __syncthreads();
    for (int i = tid; i < 32 * 64; i += 256) {
        int cll = i >> 6, tl = i & 63;
        int gc = c0 + cll, gt = t0 + tl;
        float v = 0.f;
        if (gc < C && gt < T) v = in[((size_t)b * C + gc) * T + gt] + spkS[cll];
        S[cll * 65 + tl] = v;
    }
    __syncthreads();
    // vectorized transposed store: ushort4 over 4 consecutive channels
    for (int i = tid; i < 64 * 8; i += 256) {
        int tl = i >> 3, c4 = (i & 7) * 4;
        int gt = t0 + tl, gc0 = c0 + c4;
        if (gt < T) {
            if (gc0 + 3 < C) {
                ushort4 o;
                o.x = (unsigned short)f2bf(S[(c4 + 0) * 65 + tl]);
                o.y = (unsigned short)f2bf(S[(c4 + 1) * 65 + tl]);
                o.z = (unsigned short)f2bf(S[(c4 + 2) * 65 + tl]);
                o.w = (unsigned short)f2bf(S[(c4 + 3) * 65 + tl]);
                *(ushort4*)(outT + ((size_t)b * T + gt) * C + gc0) = o;
            } else {
#pragma unroll
                for (int q = 0; q < 4; q++)
                    if (gc0 + q < C)
                        outT[((size_t)b * T + gt) * C + gc0 + q] = f2bf(S[(c4 + q) * 65 + tl]);
            }
        }
    }
}

// ---------------------------------------------------------------------------
// P: all prep in one dispatch (2126 blocks)
// ---------------------------------------------------------------------------
__global__ __launch_bounds__(256) void prep_kernel(KP p) {
    __shared__ __align__(16) float smP[16 * WPITCH];   // 24832 B
    int bid = blockIdx.x;
    if (bid < 256) { wpack_k1_lds(p.wk1, p.wk1p, smP, bid); return; }
    bid -= 256;
    if (bid < 27) { wpack_body<C2S, CS, 3, 192, 96>(p.wq1, p.wq1p, bid); return; }
    bid -= 27;
    if (bid < 40) { wpack1_body<CA, C2T, 80, 1024>(p.wk2, p.wk2p, bid); return; }
    bid -= 40;
    if (bid < 7) { wpack1_body<CA, C2S, 80, 160>(p.wq2, p.wq2p, bid); return; }
    bid -= 7;
    if (bid < 4) { wpack1_body<CA, CS, 80, 96>(p.wq3, p.wq3p, bid); return; }
    bid -= 4;
    if (bid < 1024) {
        int bx = bid & 3, by = (bid >> 2) & 15, b = bid >> 6;
        addspkT_body<CT, T2>(p.keys, p.g, p.w_kspk, p.b_kspk, p.xkT, smP, bx, by, b);
        return;
    }
    bid -= 1024;
    {
        int bx = bid & 15, by = (bid >> 4) % 3, b = bid / 48;
        addspkT_body<CS, T1>(p.queries, p.g, p.w_qspk, p.b_qspk, p.xqT, smP, bx, by, b);
    }
}

// ---------------------------------------------------------------------------
// conv3-as-GEMM body, W from global (A-frag layout), X in LDS (dbuf + reg prefetch)
// 16x16x32 bf16 MFMA: D lane reg r: row(co)=quad*4+r, col(t)=l16
// ---------------------------------------------------------------------------
template <int CIN, int COUT, int T, int KW, bool RELU, int CICH, int NC32T>
__device__ __forceinline__ void conv_body(const short* __restrict__ xT,
                                          const short* __restrict__ wp,
                                          const float* __restrict__ bias,
                                          short* __restrict__ outT,
                                          short* Xs, int bx, int by, int b) {
    constexpr int TT = 128, COT = 64;
    constexpr int PAD = KW / 2;
    constexpr int XROWS = TT + KW - 1;
    constexpr int PITCH = CICH + 8;
    constexpr int NPC = CICH / 8;
    constexpr int NC32 = CICH / 32;
    constexpr int CINP = NC32T * 32;
    constexpr int NCHK = CINP / CICH;
    constexpr int NPIECE = XROWS * NPC;
    constexpr int NLD = (NPIECE + 255) / 256;

    const int t0 = bx * TT, co0 = by * COT;
    const int tid = threadIdx.x, wave = tid >> 6, lane = tid & 63;
    const int quad = lane >> 4, l16 = lane & 15;
    const int wt = wave * 32;
    const int co16_0 = co0 >> 4;
    const short* xb = xT + (size_t)b * T * CIN;

    floatx4 acc[4][2];
#pragma unroll
    for (int mi = 0; mi < 4; mi++)
#pragma unroll
        for (int ni = 0; ni < 2; ni++) acc[mi][ni] = (floatx4){0.f, 0.f, 0.f, 0.f};

    for (int i = tid; i < NPIECE; i += 256) {
        int r = i / NPC, pp = i - r * NPC;
        int t = t0 + r - PAD, ci = pp * 8;
        uint4 v = {0u, 0u, 0u, 0u};
        if ((unsigned)t < (unsigned)T && ci + 8 <= CIN)
            v = *(const uint4*)(xb + (size_t)t * CIN + ci);
        *(uint4*)(Xs + r * PITCH + pp * 8) = v;
    }
    __syncthreads();

    for (int kc = 0; kc < NCHK; kc++) {
        uint4 tmp[NLD];
        if (NCHK > 1 && kc + 1 < NCHK) {
            int ci0n = (kc + 1) * CICH;
#pragma unroll
            for (int ld = 0; ld < NLD; ld++) {
                int i = tid + ld * 256;
                tmp[ld] = (uint4){0u, 0u, 0u, 0u};
                if (i < NPIECE) {
                    int r = i / NPC, pp = i - r * NPC;
                    int t = t0 + r - PAD, ci = ci0n + pp * 8;
                    if ((unsigned)t < (unsigned)T && ci + 8 <= CIN)
                        tmp[ld] = *(const uint4*)(xb + (size_t)t * CIN + ci);
                }
            }
        }
        const short* Xb = Xs + (NCHK > 1 ? (kc & 1) : 0) * XROWS * PITCH;
#pragma unroll
        for (int k = 0; k < KW; k++) {
#pragma unroll
            for (int kk = 0; kk < NC32; kk++) {
                int ci32 = kc * NC32 + kk;
                short8 a[4];
#pragma unroll
                for (int mi = 0; mi < 4; mi++)
                    a[mi] = *(const short8*)(wp +
                        ((size_t)((co16_0 + mi) * KW + k) * NC32T + ci32) * 512 + lane * 8);
#pragma unroll
                for (int ni = 0; ni < 2; ni++) {
                    short8 bb = *(const short8*)(Xb + (wt + ni * 16 + l16 + k) * PITCH +
                                                 kk * 32 + quad * 8);
#pragma unroll
                    for (int mi = 0; mi < 4; mi++)
                        acc[mi][ni] = __builtin_amdgcn_mfma_f32_16x16x32_bf16(a[mi], bb,
                                                                              acc[mi][ni], 0, 0, 0);
                }
            }
        }
        if (NCHK > 1 && kc + 1 < NCHK) {
            short* Xn = Xs + ((kc + 1) & 1) * XROWS * PITCH;
#pragma unroll
            for (int ld = 0; ld < NLD; ld++) {
                int i = tid + ld * 256;
                if (i < NPIECE) {
                    int r = i / NPC, pp = i - r * NPC;
                    *(uint4*)(Xn + r * PITCH + pp * 8) = tmp[ld];
                }
            }
            __syncthreads();
        }
    }
#pragma unroll
    for (int mi = 0; mi < 4; mi++) {
        int cb = co0 + mi * 16 + quad * 4;
        if (cb < COUT) {
            float4 bv = *(const float4*)(bias + cb);
#pragma unroll
            for (int ni = 0; ni < 2; ni++) {
                int t = t0 + wt + ni * 16 + l16;
                if (t < T) {
                    float v0 = acc[mi][ni][0] + bv.x, v1 = acc[mi][ni][1] + bv.y;
                    float v2 = acc[mi][ni][2] + bv.z, v3 = acc[mi][ni][3] + bv.w;
                    if (RELU) {
                        v0 = fmaxf(v0, 0.f); v1 = fmaxf(v1, 0.f);
                        v2 = fmaxf(v2, 0.f); v3 = fmaxf(v3, 0.f);
                    }
                    ushort4 o;
                    o.x = (unsigned short)f2bf(v0); o.y = (unsigned short)f2bf(v1);
                    o.z = (unsigned short)f2bf(v2); o.w = (unsigned short)f2bf(v3);
                    *(ushort4*)(outT + ((size_t)b * T + t) * COUT + cb) = o;
                }
            }
        }
    }
}

// C: key conv3 (512 blocks) + query conv3 (384 blocks) in one dispatch
__global__ __launch_bounds__(256, 2) void conv_kernel(KP p) {
    __shared__ __align__(16) short sm[18720];
    int bid = blockIdx.x;
    if (bid < 512) {
        int bx = bid & 1, by = (bid >> 1) & 15, b = bid >> 5;
        conv_body<CT, C2T, T2, 3, true, 64, 16>(p.xkT, p.wk1p, p.bk1, p.kh1T, sm, bx, by, b);
    } else {
        int r = bid - 512;
        int bx = r & 7, by = (r >> 3) % 3, b = r / 24;
        conv_body<CS, C2S, T1, 3, true, 96, 3>(p.xqT, p.wq1p, p.bq1, p.qh1T, sm, bx, by, b);
    }
}

// ---------------------------------------------------------------------------
// key 1x1: full-K GEMM (K=1024), W from global frags, X dbuf in LDS.
// Emits k_encT with row stride ENC_STR (zero pad) + k2 per row.
// ---------------------------------------------------------------------------
__device__ __forceinline__ void kgemm_body(const short* __restrict__ xT,
                                           const short* __restrict__ wp,
                                           const float* __restrict__ bias,
                                           short* __restrict__ outT,
                                           float* __restrict__ k2ws,
                                           short* sm, int bid) {
    constexpr int K = 1024, KCH = 128, PITCH = 136, NPC = 16, NCHK = 8;
    const int n0 = bid * 64;
    const int tid = threadIdx.x, wave = tid >> 6, lane = tid & 63;
    const int quad = lane >> 4, l16 = lane & 15;
    floatx4 acc[5];
#pragma unroll
    for (int mi = 0; mi < 5; mi++) acc[mi] = (floatx4){0.f, 0.f, 0.f, 0.f};

    for (int i = tid; i < 64 * NPC; i += 256) {
        int r = i / NPC, pp = i - r * NPC;
        *(uint4*)(sm + r * PITCH + pp * 8) = *(const uint4*)(xT + (size_t)(n0 + r) * K + pp * 8);
    }
    __syncthreads();
    for (int kc = 0; kc < NCHK; kc++) {
        uint4 tmp[4];
        if (kc + 1 < NCHK) {
            int ci0 = (kc + 1) * KCH;
#pragma unroll
            for (int ld = 0; ld < 4; ld++) {
                int i = tid + ld * 256;
                int r = i / NPC, pp = i - r * NPC;
                tmp[ld] = *(const uint4*)(xT + (size_t)(n0 + r) * K + ci0 + pp * 8);
            }
        }
        const short* Xb = sm + (kc & 1) * 64 * PITCH;
#pragma unroll
        for (int kk = 0; kk < 4; kk++) {
            int ci32 = kc * 4 + kk;
            short8 bb = *(const short8*)(Xb + (wave * 16 + l16) * PITCH + kk * 32 + quad * 8);
#pragma unroll
            for (int mi = 0; mi < 5; mi++) {
                short8 a = *(const short8*)(wp + ((size_t)(mi * 32 + ci32)) * 512 + lane * 8);
                acc[mi] = __builtin_amdgcn_mfma_f32_16x16x32_bf16(a, bb, acc[mi], 0, 0, 0);
            }
        }
        if (kc + 1 < NCHK) {
            short* Xn = sm + ((kc + 1) & 1) * 64 * PITCH;
#pragma unroll
            for (int ld = 0; ld < 4; ld++) {
                int i = tid + ld * 256;
                int r = i / NPC, pp = i - r * NPC;
                *(uint4*)(Xn + r * PITCH + pp * 8) = tmp[ld];
            }
            __syncthreads();
        }
    }
    int n = n0 + wave * 16 + l16;
    float sq = 0.f;
#pragma unroll
    for (int mi = 0; mi < 5; mi++) {
        int cb = mi * 16 + quad * 4;
        float4 bv = *(const float4*)(bias + cb);
        float v0 = acc[mi][0] + bv.x, v1 = acc[mi][1] + bv.y;
        float v2 = acc[mi][2] + bv.z, v3 = acc[mi][3] + bv.w;
        sq += v0 * v0 + v1 * v1 + v2 * v2 + v3 * v3;
        ushort4 o;
        o.x = (unsigned short)f2bf(v0); o.y = (unsigned short)f2bf(v1);
        o.z = (unsigned short)f2bf(v2); o.w = (unsigned short)f2bf(v3);
        *(ushort4*)(outT + (size_t)n * ENC_STR + cb) = o;
    }
    if (quad < 2) *(uint4*)(outT + (size_t)n * ENC_STR + 80 + quad * 8) = (uint4){0u, 0u, 0u, 0u};
    sq += __shfl_xor(sq, 16, 64);
    sq += __shfl_xor(sq, 32, 64);
    if (quad == 0) k2ws[n] = sq;
}

// fused query conv2(relu)+conv3, W from global frags; q_encT row stride ENC_STR
__device__ __forceinline__ void qconv23_body(const short* __restrict__ h1,
                                             const short* __restrict__ w2p,
                                             const float* __restrict__ b2,
                                             const short* __restrict__ w3p,
                                             const float* __restrict__ b3,
                                             short* __restrict__ outT, short* sm, int bid) {
    constexpr int K1 = 160, P1 = 168, NPC1 = 20, P3 = 104;
    short* Xs = sm;            // 64*168
    short* Hs = sm + 64 * P1;  // 64*104
    const int n0 = bid * 64;
    const int tid = threadIdx.x, wave = tid >> 6, lane = tid & 63;
    const int quad = lane >> 4, l16 = lane & 15;

    for (int i = tid; i < 64 * NPC1; i += 256) {
        int r = i / NPC1, pp = i - r * NPC1;
        *(uint4*)(Xs + r * P1 + pp * 8) = *(const uint4*)(h1 + (size_t)(n0 + r) * K1 + pp * 8);
    }
    if (tid < 128) *(uint4*)(Hs + (tid >> 1) * P3 + 80 + (tid & 1) * 8) = (uint4){0u, 0u, 0u, 0u};
    __syncthreads();

    floatx4 acc[5];
#pragma unroll
    for (int mi = 0; mi < 5; mi++) acc[mi] = (floatx4){0.f, 0.f, 0.f, 0.f};
#pragma unroll
    for (int kk = 0; kk < 5; kk++) {
        short8 bb = *(const short8*)(Xs + (wave * 16 + l16) * P1 + kk * 32 + quad * 8);
#pragma unroll
        for (int mi = 0; mi < 5; mi++) {
            short8 a = *(const short8*)(w2p + ((size_t)(mi * 5 + kk)) * 512 + lane * 8);
            acc[mi] = __builtin_amdgcn_mfma_f32_16x16x32_bf16(a, bb, acc[mi], 0, 0, 0);
        }
    }
#pragma unroll
    for (int mi = 0; mi < 5; mi++) {
        int cb = mi * 16 + quad * 4;
        float4 bv = *(const float4*)(b2 + cb);
        ushort4 o;
        o.x = (unsigned short)f2bf(fmaxf(acc[mi][0] + bv.x, 0.f));
        o.y = (unsigned short)f2bf(fmaxf(acc[mi][1] + bv.y, 0.f));
        o.z = (unsigned short)f2bf(fmaxf(acc[mi][2] + bv.z, 0.f));
        o.w = (unsigned short)f2bf(fmaxf(acc[mi][3] + bv.w, 0.f));
        *(ushort4*)(Hs + (wave * 16 + l16) * P3 + cb) = o;
    }
    __syncthreads();

    floatx4 acc3[5];
#pragma unroll
    for (int mi = 0; mi < 5; mi++) acc3[mi] = (floatx4){0.f, 0.f, 0.f, 0.f};
#pragma unroll
    for (int kk = 0; kk < 3; kk++) {
        short8 bb = *(const short8*)(Hs + (wave * 16 + l16) * P3 + kk * 32 + quad * 8);
#pragma unroll
        for (int mi = 0; mi < 5; mi++) {
            short8 a = *(const short8*)(w3p + ((size_t)(mi * 3 + kk)) * 512 + lane * 8);
            acc3[mi] = __builtin_amdgcn_mfma_f32_16x16x32_bf16(a, bb, acc3[mi], 0, 0, 0);
        }
    }
    int n = n0 + wave * 16 + l16;
#pragma unroll
    for (int mi = 0; mi < 5; mi++) {
        int cb = mi * 16 + quad * 4;
        float4 bv = *(const float4*)(b3 + cb);
        ushort4 o;
        o.x = (unsigned short)f2bf(acc3[mi][0] + bv.x);
        o.y = (unsigned short)f2bf(acc3[mi][1] + bv.y);
        o.z = (unsigned short)f2bf(acc3[mi][2] + bv.z);
        o.w = (unsigned short)f2bf(acc3[mi][3] + bv.w);
        *(ushort4*)(outT + (size_t)n * ENC_STR + cb) = o;
    }
    if (quad < 2) *(uint4*)(outT + (size_t)n * ENC_STR + 80 + quad * 8) = (uint4){0u, 0u, 0u, 0u};
}

// G: key 1x1 GEMM (50 blocks) + fused query conv2+conv3 (250 blocks)
__global__ __launch_bounds__(256, 2) void gemm_kernel(KP p) {
    __shared__ __align__(16) short sm[17408];
    int bid = blockIdx.x;
    if (bid < 50) kgemm_body(p.kh1T, p.wk2p, p.bk2, p.k_encT, p.k2ws, sm, bid);
    else qconv23_body(p.qh1T, p.wq2p, p.bq2, p.wq3p, p.bq3, p.q_encT, sm, bid - 50);
}

// ---------------------------------------------------------------------------
// attention: LDS-free, barrier-free.  Block = 64 t1 x b, 4 waves (16 rows each).
// ---------------------------------------------------------------------------
__device__ __forceinline__ float rmax16(float v) {
#pragma unroll
    for (int o = 1; o < 16; o <<= 1) v = fmaxf(v, __shfl_xor(v, o, 64));
    return v;
}
__device__ __forceinline__ float rsum16(float v) {
#pragma unroll
    for (int o = 1; o < 16; o <<= 1) v += __shfl_xor(v, o, 64);
    return v;
}

__global__ __launch_bounds__(256) void attn_kernel(KP p) {
    const int t10 = blockIdx.x * 64, b = blockIdx.y;
    const int tid = threadIdx.x, wave = tid >> 6, lane = tid & 63;
    const int quad = lane >> 4, l16 = lane & 15;

    float k2v[13]; int mskv[13];
#pragma unroll
    for (int n = 0; n < 13; n++) {
        int t2 = n * 16 + l16, t2c = t2 < T2 ? t2 : T2 - 1;
        k2v[n] = p.k2ws[b * T2 + t2c];
        mskv[n] = (t2 < T2) ? p.mask[b * T2 + t2] : 0;
    }
    const int t1base = t10 + wave * 16 + quad * 4;
    float pr[4][13];
#pragma unroll
    for (int r = 0; r < 4; r++) {
        int t1 = t1base + r, t1c = t1 < T1 ? t1 : T1 - 1;
#pragma unroll
        for (int n = 0; n < 13; n++) {
            int t2 = n * 16 + l16, t2c = t2 < T2 ? t2 : T2 - 1;
            pr[r][n] = p.prior[((size_t)b * T1 + t1c) * T2 + t2c];
        }
    }

    floatx4 acc[13];
#pragma unroll
    for (int n = 0; n < 13; n++) acc[n] = (floatx4){0.f, 0.f, 0.f, 0.f};
    const short* qb = p.q_encT + ((size_t)(b * T1 + t10 + wave * 16 + l16)) * ENC_STR + quad * 8;
    const short* kb = p.k_encT + ((size_t)(b * T2 + l16)) * ENC_STR + quad * 8;
#pragma unroll
    for (int kk = 0; kk < 3; kk++) {
        short8 a = *(const short8*)(qb + kk * 32);
#pragma unroll
        for (int n = 0; n < 13; n++) {
            short8 bb = *(const short8*)(kb + (size_t)n * 16 * ENC_STR + kk * 32);
            acc[n] = __builtin_amdgcn_mfma_f32_16x16x32_bf16(a, bb, acc[n], 0, 0, 0);
        }
    }

#pragma unroll
    for (int r = 0; r < 4; r++) {
        int t1 = t1base + r;
        bool t1ok = t1 < T1;
        float s[13], u[13];
        float mx = -INFINITY, mxu = -INFINITY;
#pragma unroll
        for (int n = 0; n < 13; n++) {
            int t2 = n * 16 + l16;
            float sv = (t2 < T2) ? TEMP_F * (2.f * acc[n][r] - k2v[n]) : -INFINITY;
            s[n] = sv;
            float uv = (t2 < T2) ? sv + __logf(pr[r][n] + 1e-8f) : -INFINITY;
            u[n] = uv;
            mx = fmaxf(mx, sv);
            mxu = fmaxf(mxu, (mskv[n] != 0) ? uv : -INFINITY);
        }
        float m = rmax16(mx);
        float m2 = rmax16(mxu);
        float se = 0.f, se2 = 0.f;
        float e2v[13];
#pragma unroll
        for (int n = 0; n < 13; n++) {
            se += (s[n] == -INFINITY) ? 0.f : __expf(s[n] - m);
            float e2 = (mskv[n] != 0) ? __expf(u[n] - m2) : 0.f;
            e2v[n] = e2;
            se2 += e2;
        }
        float logZ = __logf(rsum16(se));
        float invZ2 = 1.f / rsum16(se2);
        if (t1ok) {
#pragma unroll
            for (int n = 0; n < 13; n++) {
                int t2 = n * 16 + l16;
                if (t2 < T2) {
                    size_t o = ((size_t)b * T1 + t1) * T2 + t2;
                    p.out_attn[o] = e2v[n] * invZ2;
                    p.out_logp[o] = u[n] - m - logZ;
                }
            }
        }
    }
}

// ---------------------------------------------------------------------------
extern "C" void kernel_launch(void* const* d_in, const int* in_sizes, int n_in,
                              void* d_out, int out_size, void* d_ws, size_t ws_size,
                              hipStream_t stream) {
    KP p;
    p.queries = (const float*)d_in[0];
    p.keys    = (const float*)d_in[1];
    p.mask    = (const int*)d_in[2];
    p.prior   = (const float*)d_in[3];
    p.g       = (const float*)d_in[4];
    p.wk1 = (const float*)d_in[5];  p.bk1 = (const float*)d_in[6];
    p.wk2 = (const float*)d_in[7];  p.bk2 = (const float*)d_in[8];
    p.wq1 = (const float*)d_in[9];  p.bq1 = (const float*)d_in[10];
    p.wq2 = (const float*)d_in[11]; p.bq2 = (const float*)d_in[12];
    p.wq3 = (const float*)d_in[13]; p.bq3 = (const float*)d_in[14];
    p.w_kspk = (const float*)d_in[15]; p.b_kspk = (const float*)d_in[16];
    p.w_qspk = (const float*)d_in[17]; p.b_qspk = (const float*)d_in[18];

    // ---- workspace layout (shorts) ----
    short* wsS = (short*)d_ws;
    p.xkT   = wsS;                        // 16x200x512        -> 1,638,400
    p.xqT   = wsS + 1638400;              // 16x1000x80        -> 2,918,400
    p.wk1p  = wsS + 2918400;              // 3072 frags        -> 4,491,264
    p.wq1p  = wsS + 4491264;              // 108 frags         -> 4,546,560
    p.wk2p  = wsS + 4546560;              // 160 frags         -> 4,628,480
    p.wq2p  = wsS + 4628480;              // 25 frags          -> 4,641,280
    p.wq3p  = wsS + 4641280;              // 15 frags          -> 4,648,960
    p.k_encT = wsS + 4648960;             // 3216 x 96         -> 4,957,696
    p.q_encT = wsS + 4957696;             // 16032 x 96        -> 6,496,768
    p.k2ws  = (float*)d_ws + 3248384;     // 3200 fp32
    // hidden layers in d_out (consumed before attn overwrites):
    short* doS = (short*)d_out;
    p.kh1T = doS;                         // 3200x1024 (6.55 MB)
    p.qh1T = doS + 3276800;               // 16000x160 (5.12 MB)
    p.out_attn = (float*)d_out;
    p.out_logp = (float*)d_out + (size_t)NB * T1 * T2;

    // P: all prep (2126 blocks: wk1 LDS-pack 256, wq1 27, KW=1 packs 51, addspkT 1792)
    prep_kernel<<<dim3(2126), dim3(256), 0, stream>>>(p);
    // C: both k=3 convs (896 blocks)
    conv_kernel<<<dim3(896), dim3(256), 0, stream>>>(p);
    // G: key 1x1 GEMM (+k2) + fused query conv2/conv3 (300 blocks)
    gemm_kernel<<<dim3(300), dim3(256), 0, stream>>>(p);
    // A: attention (LDS-free)
    attn_kernel<<<dim3(16, NB), dim3(256), 0, stream>>>(p);
}